// Round 11
// baseline (196.955 us; speedup 1.0000x reference)
//
#include <hip/hip_runtime.h>
#include <math.h>

static constexpr int Bn = 8, Ln = 1024, Dm = 512, Hn = 8, DhN = 64;

typedef short bf16x8 __attribute__((ext_vector_type(8)));
typedef float f32x4 __attribute__((ext_vector_type(4)));
typedef _Float16 f16x4 __attribute__((ext_vector_type(4)));
typedef _Float16 f16x8 __attribute__((ext_vector_type(8)));
typedef unsigned int u32x4 __attribute__((ext_vector_type(4)));

// 0.125 * log2(e): folds the 1/sqrt(dh) scale AND the exp->exp2 conversion
#define QSCALE 0.1803368801111137f

static __device__ __forceinline__ unsigned short f2b(float f) {
  union { float f; unsigned int u; } x;
  x.f = f;
  unsigned int u = x.u;
  unsigned int r = (u + 0x7FFFu + ((u >> 16) & 1u)) >> 16;  // RNE
  return (unsigned short)r;
}

#define GLDS16(g, l)                                                        \
  __builtin_amdgcn_global_load_lds((const __attribute__((address_space(1))) void*)(g), \
                                   (__attribute__((address_space(3))) void*)(l), 16, 0, 0)

// ---------------- K1: LayerNorm + weight conversions + pos-GEMM (inline PE) ----------------
// b < 8192: LN row.  8192..8960: w_qkv conv.  8960..9216: w_out conv.
// b >= 9216: pos GEMM block (128 blocks): pos = pe @ w_pos^T with pe computed inline,
//            w_pos converted f32->bf16 inline; epilogue writes posb (f32, (H,L,Dh)) and
//            biasp[h,l] = QSCALE * sum_dh vb[h,dh]*pos[l,h,dh].
__global__ __launch_bounds__(256) void prep1(const float* __restrict__ x,
                                             const float* __restrict__ gamma,
                                             const float* __restrict__ beta,
                                             unsigned short* __restrict__ xn,
                                             const float* __restrict__ wq, unsigned short* __restrict__ wqb,
                                             const float* __restrict__ wo, unsigned short* __restrict__ wob,
                                             const float* __restrict__ wpos,
                                             const float* __restrict__ vbias,
                                             float* __restrict__ posb,
                                             float* __restrict__ biasp) {
  __shared__ float red[8];
  __shared__ alignas(16) unsigned short Ap[4096];
  __shared__ alignas(16) unsigned short Bp[4096];
  __shared__ float Bred[4][32];
  int b = blockIdx.x;
  int t = threadIdx.x;
  if (b < 8192) {
    const float2 v = *(const float2*)(x + (size_t)b * Dm + t * 2);
    float s = v.x + v.y;
    float sq = v.x * v.x + v.y * v.y;
#pragma unroll
    for (int off = 32; off > 0; off >>= 1) {
      s += __shfl_down(s, off);
      sq += __shfl_down(sq, off);
    }
    int wave = t >> 6, lane = t & 63;
    if (lane == 0) { red[wave * 2] = s; red[wave * 2 + 1] = sq; }
    __syncthreads();
    float S = red[0] + red[2] + red[4] + red[6];
    float SQ = red[1] + red[3] + red[5] + red[7];
    float mu = S * (1.0f / Dm);
    float var = SQ * (1.0f / Dm) - mu * mu;
    float rstd = rsqrtf(var + 1e-5f);
    int c = t * 2;
    ushort2 o;
    o.x = f2b((v.x - mu) * rstd * gamma[c] + beta[c]);
    o.y = f2b((v.y - mu) * rstd * gamma[c + 1] + beta[c + 1]);
    *(ushort2*)(xn + (size_t)b * Dm + c) = o;
  } else if (b < 9216) {
    const float* src;
    unsigned short* dst;
    int off;
    if (b < 8960) { src = wq; dst = wqb; off = b - 8192; }
    else { src = wo; dst = wob; off = b - 8960; }
    int i = off * 256 + t;
    float4 v = *(const float4*)(src + (size_t)i * 4);
    ushort4 o;
    o.x = f2b(v.x); o.y = f2b(v.y); o.z = f2b(v.z); o.w = f2b(v.w);
    *(ushort4*)(dst + (size_t)i * 4) = o;
  } else {
    // ---- pos GEMM: 64x64 tile, M=1024 (positions), per-head N-tile ----
    int pb = b - 9216;              // [0,128)
    int by = pb >> 3, bx = pb & 7;  // m-tile, head
    const int lane = t & 63, w = t >> 6;
    const int c = lane & 15, q8 = lane >> 4;
    const int wm = (w & 1) * 32, wn = (w >> 1) * 32;
    const int m0 = by * 64, n0 = bx * 64;
    f32x4 acc[2][2];
#pragma unroll
    for (int i = 0; i < 2; ++i)
#pragma unroll
      for (int j = 0; j < 2; ++j) acc[i][j] = (f32x4){0.f, 0.f, 0.f, 0.f};
    const int srow = lane >> 3;
    const int sgr = (lane & 7) ^ srow;
    for (int k0 = 0; k0 < 512; k0 += 64) {
      __syncthreads();
#pragma unroll
      for (int j = 0; j < 2; ++j) {
        int r = j * 32 + w * 8 + srow;
        int l = m0 + r;
        int kbase = k0 + sgr * 8;  // even
        // B: w_pos f32 -> bf16 inline
        const float* wr = wpos + (size_t)(n0 + r) * 512 + kbase;
        float4 b0 = *(const float4*)wr;
        float4 b1 = *(const float4*)(wr + 4);
        u32x4 bw;
        bw[0] = (unsigned)f2b(b0.x) | ((unsigned)f2b(b0.y) << 16);
        bw[1] = (unsigned)f2b(b0.z) | ((unsigned)f2b(b0.w) << 16);
        bw[2] = (unsigned)f2b(b1.x) | ((unsigned)f2b(b1.y) << 16);
        bw[3] = (unsigned)f2b(b1.z) | ((unsigned)f2b(b1.w) << 16);
        // A: pe[l][k] computed inline; k even -> cos, odd -> sin
        u32x4 aw;
#pragma unroll
        for (int e = 0; e < 4; ++e) {
          int k1 = kbase + e * 2;
          float f1 = __expf(-0.0359778921f * (float)k1);
          float f2_ = __expf(-0.0359778921f * (float)(k1 + 1));
          float v1 = cosf((float)(l - k1) * f1);
          float v2 = sinf((float)(l - k1 - 1) * f2_);
          aw[e] = (unsigned)f2b(v1) | ((unsigned)f2b(v2) << 16);
        }
        *(u32x4*)&Ap[(j * 256 + w * 64 + lane) * 8] = aw;
        *(u32x4*)&Bp[(j * 256 + w * 64 + lane) * 8] = bw;
      }
      __syncthreads();
#pragma unroll
      for (int kk = 0; kk < 2; ++kk) {
        bf16x8 a[2], bb_[2];
        const int q = kk * 4 + q8;
#pragma unroll
        for (int i = 0; i < 2; ++i) {
          int rr = wm + i * 16 + c;
          a[i] = *(const bf16x8*)&Ap[(rr * 8 + (q ^ (rr & 7))) * 8];
        }
#pragma unroll
        for (int j = 0; j < 2; ++j) {
          int rr = wn + j * 16 + c;
          bb_[j] = *(const bf16x8*)&Bp[(rr * 8 + (q ^ (rr & 7))) * 8];
        }
#pragma unroll
        for (int i = 0; i < 2; ++i)
#pragma unroll
          for (int j = 0; j < 2; ++j)
            acc[i][j] = __builtin_amdgcn_mfma_f32_16x16x32_bf16(a[i], bb_[j], acc[i][j], 0, 0, 0);
      }
    }
    // epilogue: write posb + reduce vb.pos
    float part[2][4];
#pragma unroll
    for (int i = 0; i < 2; ++i)
#pragma unroll
      for (int r = 0; r < 4; ++r) part[i][r] = 0.0f;
#pragma unroll
    for (int i = 0; i < 2; ++i) {
#pragma unroll
      for (int r = 0; r < 4; ++r) {
        int m = m0 + wm + i * 16 + q8 * 4 + r;
#pragma unroll
        for (int j = 0; j < 2; ++j) {
          int n = n0 + wn + j * 16 + c;  // h*64+dh
          float val = acc[i][j][r];
          posb[(size_t)((bx << 10) + m) * 64 + (n & 63)] = val;
          part[i][r] += vbias[n] * val;
        }
      }
    }
#pragma unroll
    for (int i = 0; i < 2; ++i)
#pragma unroll
      for (int r = 0; r < 4; ++r) {
        float v = part[i][r];
        v += __shfl_xor(v, 1);
        v += __shfl_xor(v, 2);
        v += __shfl_xor(v, 4);
        v += __shfl_xor(v, 8);
        part[i][r] = v;
      }
    if (c == 0) {
#pragma unroll
      for (int i = 0; i < 2; ++i)
#pragma unroll
        for (int r = 0; r < 4; ++r) Bred[w][i * 16 + q8 * 4 + r] = part[i][r];
    }
    __syncthreads();
    if (t < 64) {
      float s = (t < 32) ? (Bred[0][t] + Bred[2][t]) : (Bred[1][t - 32] + Bred[3][t - 32]);
      biasp[(bx << 10) + m0 + t] = s * QSCALE;
    }
  }
}

// ---------------- K2/K4: bf16 MFMA NT GEMM, 64x64 tile, fused epilogues ----------------
// mode 0 (QKV): part0 -> q bf16 prescaled; part1 -> K'=k+pos bf16 + biasb reduction;
//               part2 -> vt fp16 transposed-permuted scatter.
// mode 2 (out): outf f32 row-major (N=512).
__global__ __launch_bounds__(256, 6) void gemm_mfma(const unsigned short* __restrict__ A,
                                                    const unsigned short* __restrict__ Bw,
                                                    const float* __restrict__ bias,
                                                    float* __restrict__ outf,
                                                    unsigned short* __restrict__ oq,
                                                    unsigned short* __restrict__ kp,
                                                    unsigned short* __restrict__ vt,
                                                    const float* __restrict__ posb,
                                                    const float* __restrict__ biasp,
                                                    float* __restrict__ biasb,
                                                    const float* __restrict__ ubias,
                                                    int K, int mode) {
  __shared__ alignas(16) unsigned short As[64 * 64];
  __shared__ alignas(16) unsigned short Bs[64 * 64];
  __shared__ float Bred[4][32];
  int by = blockIdx.y, bx = blockIdx.x;
  const int t = threadIdx.x;
  const int lane = t & 63, w = t >> 6;
  const int c = lane & 15, q8 = lane >> 4;
  const int wm = (w & 1) * 32, wn = (w >> 1) * 32;
  const int m0 = by * 64, n0 = bx * 64;

  f32x4 acc[2][2];
#pragma unroll
  for (int i = 0; i < 2; ++i)
#pragma unroll
    for (int j = 0; j < 2; ++j) acc[i][j] = (f32x4){0.f, 0.f, 0.f, 0.f};

  const int srow = lane >> 3;
  const int sgr = (lane & 7) ^ srow;

  for (int k0 = 0; k0 < K; k0 += 64) {
    __syncthreads();
#pragma unroll
    for (int j = 0; j < 2; ++j) {
      int r = j * 32 + w * 8 + srow;
      GLDS16(A + (size_t)(m0 + r) * K + k0 + sgr * 8, As + (j * 256 + w * 64 + lane) * 8);
      GLDS16(Bw + (size_t)(n0 + r) * K + k0 + sgr * 8, Bs + (j * 256 + w * 64 + lane) * 8);
    }
    __syncthreads();
#pragma unroll
    for (int kk = 0; kk < 2; ++kk) {
      bf16x8 a[2], b[2];
      const int q = kk * 4 + q8;
#pragma unroll
      for (int i = 0; i < 2; ++i) {
        int r = wm + i * 16 + c;
        a[i] = *(const bf16x8*)&As[(r * 8 + (q ^ (r & 7))) * 8];
      }
#pragma unroll
      for (int j = 0; j < 2; ++j) {
        int r = wn + j * 16 + c;
        b[j] = *(const bf16x8*)&Bs[(r * 8 + (q ^ (r & 7))) * 8];
      }
#pragma unroll
      for (int i = 0; i < 2; ++i)
#pragma unroll
        for (int j = 0; j < 2; ++j)
          acc[i][j] = __builtin_amdgcn_mfma_f32_16x16x32_bf16(a[i], b[j], acc[i][j], 0, 0, 0);
    }
  }
  const bool isK = (mode == 0) && (bx >= 8) && (bx < 16);
  float uk[2][4];
#pragma unroll
  for (int i = 0; i < 2; ++i)
#pragma unroll
    for (int r = 0; r < 4; ++r) uk[i][r] = 0.0f;
#pragma unroll
  for (int i = 0; i < 2; ++i) {
#pragma unroll
    for (int r = 0; r < 4; ++r) {
      int m = m0 + wm + i * 16 + q8 * 4 + r;
#pragma unroll
      for (int j = 0; j < 2; ++j) {
        int n = n0 + wn + j * 16 + c;
        float val = acc[i][j][r] + (bias ? bias[n] : 0.0f);
        if (mode == 0) {
          int part = n >> 9, h = (n >> 6) & 7, dh = n & 63;
          int bb = m >> 10, l = m & 1023;
          size_t idx = (size_t)((bb * 8 + h) * 1024 + l) * 64 + dh;
          if (part == 0) {
            oq[idx] = f2b(val * QSCALE);
          } else if (part == 1) {
            float pv = posb[(size_t)((h << 10) + l) * 64 + dh];
            kp[idx] = f2b(val + pv);
            uk[i][r] += ubias[h * 64 + dh] * val;
          } else {
            int lb = l & 63;
            int perm = ((lb >> 2) & 3) * 16 + ((lb >> 4) & 3) * 4 + (lb & 3);
            union { _Float16 hf; unsigned short u; } cv;
            cv.hf = (_Float16)val;
            vt[(size_t)(bb * 8 + h) * 65536 + (size_t)dh * 1024 + (l & 960) + perm] = cv.u;
          }
        } else {
          outf[(size_t)m * 512 + n] = val;
        }
      }
    }
  }
  if (isK) {
#pragma unroll
    for (int i = 0; i < 2; ++i)
#pragma unroll
      for (int r = 0; r < 4; ++r) {
        float v = uk[i][r];
        v += __shfl_xor(v, 1);
        v += __shfl_xor(v, 2);
        v += __shfl_xor(v, 4);
        v += __shfl_xor(v, 8);
        uk[i][r] = v;
      }
    if (c == 0) {
#pragma unroll
      for (int i = 0; i < 2; ++i)
#pragma unroll
        for (int r = 0; r < 4; ++r) Bred[w][i * 16 + q8 * 4 + r] = uk[i][r];
    }
    __syncthreads();
    if (t < 64) {
      float s = (t < 32) ? (Bred[0][t] + Bred[2][t]) : (Bred[1][t - 32] + Bred[3][t - 32]);
      int m = m0 + t;
      int bb = m >> 10, l = m & 1023;
      int h = (n0 >> 6) & 7;
      biasb[(size_t)(bb * 8 + h) * 1024 + l] = s * QSCALE + biasp[(h << 10) + l];
    }
  }
}

// ---------------- Flash attention v5 (unchanged): Q-tile 128 = 4 waves x 2 groups, BK=128 ----------------
__global__ __launch_bounds__(256, 2) void flash_mfma(const unsigned short* __restrict__ qbf,
                                                     const unsigned short* __restrict__ kbf,
                                                     const unsigned short* __restrict__ vt,
                                                     const float* __restrict__ bias,
                                                     unsigned short* __restrict__ attn_out) {
  __shared__ alignas(16) unsigned short Ks[2][64 * 64];
  __shared__ alignas(16) unsigned short Vs[2][64 * 64];
  __shared__ alignas(16) float Bls[1024];
  const int t = threadIdx.x;
  const int lane = t & 63, w = t >> 6;
  const int c = lane & 15, q8 = lane >> 4;
  const int cc7 = c & 7;
  const int bh = blockIdx.y, qt = blockIdx.x;
  const unsigned short* qg = qbf + (size_t)bh * 65536;
  const unsigned short* kg = kbf + (size_t)bh * 65536;
  const unsigned short* vg = vt + (size_t)bh * 65536;
  const float* bg = bias + (size_t)bh * 1024;

  GLDS16(bg + t * 4, Bls + t * 4);

  bf16x8 bq[2][2];
#pragma unroll
  for (int g = 0; g < 2; ++g) {
    int qlg = qt * 128 + g * 64 + w * 16 + c;
    bq[g][0] = *(const bf16x8*)(qg + (size_t)qlg * 64 + q8 * 8);
    bq[g][1] = *(const bf16x8*)(qg + (size_t)qlg * 64 + 32 + q8 * 8);
  }

  float m_st[2] = {-INFINITY, -INFINITY};
  float l_st[2] = {0.0f, 0.0f};
  f32x4 o[2][4];
#pragma unroll
  for (int g = 0; g < 2; ++g)
#pragma unroll
    for (int i = 0; i < 4; ++i) o[g][i] = (f32x4){0.f, 0.f, 0.f, 0.f};

  const int srow = lane >> 3;
  const int sgr = (lane & 7) ^ srow;
  const int r0 = w * 16 + srow;

  u32x4 pk[2][2], pv[2][2];
#pragma unroll
  for (int h = 0; h < 2; ++h)
#pragma unroll
    for (int j = 0; j < 2; ++j) {
      int r = r0 + j * 8;
      pk[h][j] = *(const u32x4*)(kg + (size_t)(h * 64 + r) * 64 + sgr * 8);
      pv[h][j] = *(const u32x4*)(vg + (size_t)r * 1024 + h * 64 + sgr * 8);
    }

  for (int it = 0; it < 8; ++it) {
    __syncthreads();
#pragma unroll
    for (int h = 0; h < 2; ++h)
#pragma unroll
      for (int j = 0; j < 2; ++j) {
        int r = r0 + j * 8;
        *(u32x4*)&Ks[h][(r * 8 + (lane & 7)) * 8] = pk[h][j];
        *(u32x4*)&Vs[h][(r * 8 + (lane & 7)) * 8] = pv[h][j];
      }
    __syncthreads();
    if (it < 7) {
#pragma unroll
      for (int h = 0; h < 2; ++h)
#pragma unroll
        for (int j = 0; j < 2; ++j) {
          int r = r0 + j * 8;
          pk[h][j] = *(const u32x4*)(kg + (size_t)((it + 1) * 128 + h * 64 + r) * 64 + sgr * 8);
          pv[h][j] = *(const u32x4*)(vg + (size_t)r * 1024 + (it + 1) * 128 + h * 64 + sgr * 8);
        }
    }

    f32x4 sc[2][2][4];
#pragma unroll
    for (int h = 0; h < 2; ++h) {
#pragma unroll
      for (int nt = 0; nt < 4; ++nt) {
        f32x4 ci = *(const f32x4*)&Bls[it * 128 + h * 64 + nt * 16 + q8 * 4];
        const int row = nt * 16 + c;
        bf16x8 ak0 = *(const bf16x8*)&Ks[h][(row * 8 + (q8 ^ cc7)) * 8];
        bf16x8 ak1 = *(const bf16x8*)&Ks[h][(row * 8 + ((q8 + 4) ^ cc7)) * 8];
#pragma unroll
        for (int g = 0; g < 2; ++g) {
          f32x4 z = __builtin_amdgcn_mfma_f32_16x16x32_bf16(ak0, bq[g][0], ci, 0, 0, 0);
          sc[g][h][nt] = __builtin_amdgcn_mfma_f32_16x16x32_bf16(ak1, bq[g][1], z, 0, 0, 0);
        }
      }
    }
    float mx[2];
#pragma unroll
    for (int g = 0; g < 2; ++g) {
      float m = sc[g][0][0][0];
#pragma unroll
      for (int h = 0; h < 2; ++h)
#pragma unroll
        for (int nt = 0; nt < 4; ++nt)
#pragma unroll
          for (int r = 0; r < 4; ++r) m = fmaxf(m, sc[g][h][nt][r]);
      mx[g] = m;
    }
    {
      float s0 = __shfl_xor(mx[0], 16);
      float s1 = __shfl_xor(mx[1], 16);
      mx[0] = fmaxf(mx[0], s0);
      mx[1] = fmaxf(mx[1], s1);
      s0 = __shfl_xor(mx[0], 32);
      s1 = __shfl_xor(mx[1], 32);
      mx[0] = fmaxf(mx[0], s0);
      mx[1] = fmaxf(mx[1], s1);
    }
    f16x4 pf[2][2][4];
#pragma unroll
    for (int g = 0; g < 2; ++g) {
      float mn = fmaxf(m_st[g], mx[g]);
      float al = __builtin_amdgcn_exp2f(m_st[g] - mn);
      float su = 0.0f;
#pragma unroll
      for (int h = 0; h < 2; ++h)
#pragma unroll
        for (int nt = 0; nt < 4; ++nt)
#pragma unroll
          for (int r = 0; r < 4; ++r) {
            float p = __builtin_amdgcn_exp2f(sc[g][h][nt][r] - mn);
            su += p;
            pf[g][h][nt][r] = (_Float16)p;
          }
      l_st[g] = l_st[g] * al + su;
      m_st[g] = mn;
#pragma unroll
      for (int i = 0; i < 4; ++i) o[g][i] *= al;
    }
#pragma unroll
    for (int i = 0; i < 4; ++i) {
      const int row = i * 16 + c;
#pragma unroll
      for (int h = 0; h < 2; ++h) {
        f16x8 v01 = *(const f16x8*)&Vs[h][(row * 8 + ((2 * q8) ^ cc7)) * 8];
        f16x8 v23 = *(const f16x8*)&Vs[h][(row * 8 + ((2 * q8 + 1) ^ cc7)) * 8];
        f16x4 a0 = {v01[0], v01[1], v01[2], v01[3]};
        f16x4 a1 = {v01[4], v01[5], v01[6], v01[7]};
        f16x4 a2 = {v23[0], v23[1], v23[2], v23[3]};
        f16x4 a3 = {v23[4], v23[5], v23[6], v23[7]};
#pragma unroll
        for (int g = 0; g < 2; ++g) {
          o[g][i] = __builtin_amdgcn_mfma_f32_16x16x16f16(a0, pf[g][h][0], o[g][i], 0, 0, 0);
          o[g][i] = __builtin_amdgcn_mfma_f32_16x16x16f16(a1, pf[g][h][1], o[g][i], 0, 0, 0);
          o[g][i] = __builtin_amdgcn_mfma_f32_16x16x16f16(a2, pf[g][h][2], o[g][i], 0, 0, 0);
          o[g][i] = __builtin_amdgcn_mfma_f32_16x16x16f16(a3, pf[g][h][3], o[g][i], 0, 0, 0);
        }
      }
    }
  }
  float lt0 = l_st[0], lt1 = l_st[1];
  {
    float s0 = __shfl_xor(lt0, 16);
    float s1 = __shfl_xor(lt1, 16);
    lt0 += s0; lt1 += s1;
    s0 = __shfl_xor(lt0, 32);
    s1 = __shfl_xor(lt1, 32);
    lt0 += s0; lt1 += s1;
  }
  const int bidx = bh >> 3, h = bh & 7;
#pragma unroll
  for (int g = 0; g < 2; ++g) {
    int qlg = qt * 128 + g * 64 + w * 16 + c;
    float inv = 1.0f / (g == 0 ? lt0 : lt1);
    size_t base = (size_t)(bidx * 1024 + qlg) * 512 + h * 64;
#pragma unroll
    for (int i = 0; i < 4; ++i) {
      ushort4 ov4;
      ov4.x = f2b(o[g][i][0] * inv);
      ov4.y = f2b(o[g][i][1] * inv);
      ov4.z = f2b(o[g][i][2] * inv);
      ov4.w = f2b(o[g][i][3] * inv);
      *(ushort4*)(attn_out + base + i * 16 + q8 * 4) = ov4;
    }
  }
}

extern "C" void kernel_launch(void* const* d_in, const int* in_sizes, int n_in,
                              void* d_out, int out_size, void* d_ws, size_t ws_size,
                              hipStream_t stream) {
  const float* x      = (const float*)d_in[0];
  const float* gamma  = (const float*)d_in[1];
  const float* beta   = (const float*)d_in[2];
  const float* w_qkv  = (const float*)d_in[3];
  const float* b_qkv  = (const float*)d_in[4];
  const float* w_pos  = (const float*)d_in[5];
  const float* w_out  = (const float*)d_in[6];
  const float* b_out  = (const float*)d_in[7];
  const float* u_bias = (const float*)d_in[8];
  const float* v_bias = (const float*)d_in[9];
  float* out = (float*)d_out;

  unsigned short* wsu = (unsigned short*)d_ws;
  unsigned short* xnb   = wsu;                    // 4M ushort
  unsigned short* wqkvb = wsu + 4194304;          // 768K
  unsigned short* woutb = wsu + 4980736;          // 256K
  unsigned short* qbf   = wsu + 5242880;          // 4M (bf16, pre-scaled)
  unsigned short* kbf   = wsu + 9437184;          // 4M (K' bf16, written fused)
  unsigned short* vtb   = wsu + 13631488;         // 4M (fp16, transposed-permuted, written fused)
  unsigned short* attnb = wsu + 17825792;         // 4M (bf16)
  float* posb  = (float*)(wsu + 22020096);        // 512K floats (H,L,Dh)
  float* biasb = (float*)(wsu + 23068672);        // 64K floats (B,H,L)
  float* biasp = (float*)(wsu + 23199744);        // 8K floats (H,L)

  // K1: LN (8192) + w_qkv conv (768) + w_out conv (256) + pos GEMM (128)
  prep1<<<9344, 256, 0, stream>>>(x, gamma, beta, xnb, w_qkv, wqkvb, w_out, woutb,
                                  w_pos, v_bias, posb, biasp);
  // K2: QKV GEMM with fused fold/bias/vt-scatter epilogue
  gemm_mfma<<<dim3(24, 128), 256, 0, stream>>>(xnb, wqkvb, b_qkv, nullptr, qbf, kbf, vtb,
                                               posb, biasp, biasb, u_bias, 512, 0);
  // K3: flash attention
  flash_mfma<<<dim3(8, 64), 256, 0, stream>>>(qbf, kbf, vtb, biasb, attnb);
  // K4: out GEMM
  gemm_mfma<<<dim3(8, 128), 256, 0, stream>>>(attnb, woutb, b_out, out, nullptr, nullptr, nullptr,
                                              nullptr, nullptr, nullptr, nullptr, 512, 2);
}